// Round 1
// 390.952 us; speedup vs baseline: 1.0272x; 1.0272x over previous
//
#include <hip/hip_runtime.h>

#define BINS 10

// One row (C=16) per thread: 4x float4 loads per row (64 B/thread/row).
// Consecutive lanes read consecutive rows; each load instr strides 64 B but the
// 4 loads together cover the wave's 4 KiB contiguous region (L1 catches reuse).
// All softmax / binning math runs on every lane (no divergence, no shuffles).
// Histogram accumulates in per-thread REGISTERS (statically-indexed unrolled
// loop -> no scratch), eliminating the per-row LDS f64 atomics that serialized
// on the 2 hot bins (g concentrates at bins 0 and 9 for this data).
__global__ __launch_bounds__(256) void ghm_main(const float* __restrict__ x,
                                                const int* __restrict__ tgt,
                                                double* __restrict__ g_sum,
                                                unsigned int* __restrict__ g_cnt,
                                                int n_rows) {
    __shared__ double s_sum[BINS];
    __shared__ unsigned int s_cnt[BINS];
    if (threadIdx.x < BINS) { s_sum[threadIdx.x] = 0.0; s_cnt[threadIdx.x] = 0u; }
    __syncthreads();

    // Exact fp32 edges matching jnp.arange(11)/10 (correctly-rounded k/10).
    const float edges[BINS + 1] = {0.0f, 0.1f, 0.2f, 0.3f, 0.4f, 0.5f,
                                   0.6f, 0.7f, 0.8f, 0.9f, 1.0f};

    double acc[BINS];
    unsigned int cnt[BINS];
#pragma unroll
    for (int k = 0; k < BINS; ++k) { acc[k] = 0.0; cnt[k] = 0u; }

    const int tid = blockIdx.x * blockDim.x + threadIdx.x;
    const int nthreads = gridDim.x * blockDim.x;
    const float4* __restrict__ x4 = (const float4*)x;

    for (int row = tid; row < n_rows; row += nthreads) {
        const float4 a = x4[row * 4 + 0];
        const float4 b = x4[row * 4 + 1];
        const float4 c = x4[row * 4 + 2];
        const float4 d = x4[row * 4 + 3];
        const int t = tgt[row];  // 0 or 1 for this problem (classes 0..3 in 'a')

        // max over 16 (fmax is exact/order-independent)
        const float m = fmaxf(fmaxf(fmaxf(fmaxf(a.x, a.y), fmaxf(a.z, a.w)),
                                    fmaxf(fmaxf(b.x, b.y), fmaxf(b.z, b.w))),
                              fmaxf(fmaxf(fmaxf(c.x, c.y), fmaxf(c.z, c.w)),
                                    fmaxf(fmaxf(d.x, d.y), fmaxf(d.z, d.w))));

        // sum of exp(x-m): serial within each quad, then pairwise tree —
        // bit-identical rounding order to the previous (verified) kernel.
        const float s0 = expf(a.x - m) + expf(a.y - m) + expf(a.z - m) + expf(a.w - m);
        const float s1 = expf(b.x - m) + expf(b.y - m) + expf(b.z - m) + expf(b.w - m);
        const float s2 = expf(c.x - m) + expf(c.y - m) + expf(c.z - m) + expf(c.w - m);
        const float s3 = expf(d.x - m) + expf(d.y - m) + expf(d.z - m) + expf(d.w - m);
        const float s = (s0 + s1) + (s2 + s3);

        const float xt = (t == 0) ? a.x : ((t == 1) ? a.y : ((t == 2) ? a.z : a.w));
        const float logp = xt - m - logf(s);   // log_softmax at target
        const float p = expf(logp);            // p_t
        const float g = fabsf(p - (float)t);   // gradient norm

        // searchsorted(edges, g, 'right') - 1, clipped to [0, BINS-1]
        int bidx = 0;
#pragma unroll
        for (int k = 1; k <= BINS; ++k) bidx += (g >= edges[k]) ? 1 : 0;
        if (bidx > BINS - 1) bidx = BINS - 1;

        // Register histogram: static indices only (unrolled predicated adds).
        const double nll = (double)(-logp);
#pragma unroll
        for (int k = 0; k < BINS; ++k) {
            const bool h = (bidx == k);
            acc[k] += h ? nll : 0.0;
            cnt[k] += h ? 1u : 0u;
        }
    }

    // Per-block LDS reduction (once per thread, skip empty bins — typically
    // only ~2-4 of 10 bins are nonzero per thread).
#pragma unroll
    for (int k = 0; k < BINS; ++k) {
        if (cnt[k] != 0u) {
            atomicAdd(&s_cnt[k], cnt[k]);
            atomicAdd(&s_sum[k], acc[k]);
        }
    }
    __syncthreads();

    // Block -> global, padded to 128-B stride per bin so different bins land in
    // different L2 lines/banks (2048 blocks hammer these at kernel end).
    if (threadIdx.x < BINS) {
        if (s_cnt[threadIdx.x] != 0u) {
            atomicAdd(&g_cnt[threadIdx.x * 32], s_cnt[threadIdx.x]);
            atomicAdd(&g_sum[threadIdx.x * 16], s_sum[threadIdx.x]);
        }
    }
}

__global__ void ghm_final(const double* __restrict__ g_sum,
                          const unsigned int* __restrict__ g_cnt,
                          float* __restrict__ out, int n_rows) {
    if (threadIdx.x == 0 && blockIdx.x == 0) {
        const double scale = (double)n_rows / (double)BINS;
        double total = 0.0;
        for (int b = 0; b < BINS; ++b) {
            double c = (double)g_cnt[b * 32];
            if (c < 1.0) c = 1.0;
            total += g_sum[b * 16] / c;
        }
        out[0] = (float)(total * scale);
    }
}

extern "C" void kernel_launch(void* const* d_in, const int* in_sizes, int n_in,
                              void* d_out, int out_size, void* d_ws, size_t ws_size,
                              hipStream_t stream) {
    const float* x = (const float*)d_in[0];
    const int* tgt = (const int*)d_in[1];
    const int n_rows = in_sizes[1];  // N = 4194304 (inputs are N x 16)

    // Padded layout: g_sum = 10 bins * 16 doubles (128 B stride) at d_ws,
    //                g_cnt = 10 bins * 32 uints   (128 B stride) at d_ws+2048.
    double* g_sum = (double*)d_ws;
    unsigned int* g_cnt = (unsigned int*)((char*)d_ws + 2048);

    // d_ws is re-poisoned to 0xAA before every timed launch — zero the histogram.
    hipMemsetAsync(d_ws, 0, 4096, stream);

    const int block = 256;
    const int grid = 2048;  // 524288 threads -> 8 rows/thread grid-stride
    ghm_main<<<grid, block, 0, stream>>>(x, tgt, g_sum, g_cnt, n_rows);
    ghm_final<<<1, 64, 0, stream>>>(g_sum, g_cnt, (float*)d_out, n_rows);
}